// Round 1
// baseline (430.036 us; speedup 1.0000x reference)
//
#include <hip/hip_runtime.h>

// LSTM: B=2048 independent sequences, T=2048 serial steps, H=16, IN=1.
// One wave per batch element: lane l = gate row l (i:0-15, f:16-31, g:32-47, o:48-63).
// h replicated per 16-lane DPP row; matvec via v_fmac + row_ror DPP against
// pre-rotated W_hh registers. Full fp32 recurrence.

__device__ __forceinline__ float i2f(int i) { return __int_as_float(i); }
__device__ __forceinline__ int   f2i(float f) { return __float_as_int(f); }

// DPP row rotate (within 16-lane rows). Direction probed at runtime.
#define RORF(hi_, n) i2f(__builtin_amdgcn_mov_dpp((hi_), 0x120 + (n), 0xF, 0xF, true))

#define LOG2E 1.44269504088896340736f

#define STEP(s_imm) {                                                        \
    float fx_ = i2f(__builtin_amdgcn_readlane(f2i(xblk), (s_imm)));          \
    float aA_ = fmaf(wih, fx_, bias);                                        \
    int   hi_ = f2i(hcur);                                                   \
    aA_ = fmaf(hcur,          w[0],  aA_);                                   \
    aA_ = fmaf(RORF(hi_, 1),  w[1],  aA_);                                   \
    aA_ = fmaf(RORF(hi_, 2),  w[2],  aA_);                                   \
    aA_ = fmaf(RORF(hi_, 3),  w[3],  aA_);                                   \
    aA_ = fmaf(RORF(hi_, 4),  w[4],  aA_);                                   \
    aA_ = fmaf(RORF(hi_, 5),  w[5],  aA_);                                   \
    aA_ = fmaf(RORF(hi_, 6),  w[6],  aA_);                                   \
    aA_ = fmaf(RORF(hi_, 7),  w[7],  aA_);                                   \
    float aB_ = RORF(hi_, 8) * w[8];                                         \
    aB_ = fmaf(RORF(hi_, 9),  w[9],  aB_);                                   \
    aB_ = fmaf(RORF(hi_, 10), w[10], aB_);                                   \
    aB_ = fmaf(RORF(hi_, 11), w[11], aB_);                                   \
    aB_ = fmaf(RORF(hi_, 12), w[12], aB_);                                   \
    aB_ = fmaf(RORF(hi_, 13), w[13], aB_);                                   \
    aB_ = fmaf(RORF(hi_, 14), w[14], aB_);                                   \
    aB_ = fmaf(RORF(hi_, 15), w[15], aB_);                                   \
    float acc_ = aA_ + aB_;                                                  \
    float e_   = __builtin_amdgcn_exp2f(mco * acc_);                         \
    float r_   = __builtin_amdgcn_rcpf(1.0f + e_);                           \
    float act_ = fmaf(aco, r_, bco);                                         \
    int   ai_  = f2i(act_);                                                  \
    float gi_  = i2f(__builtin_amdgcn_ds_bpermute(addr_i, ai_));             \
    float gf_  = i2f(__builtin_amdgcn_ds_bpermute(addr_f, ai_));             \
    float gg_  = i2f(__builtin_amdgcn_ds_bpermute(addr_g, ai_));             \
    float go_  = i2f(__builtin_amdgcn_ds_bpermute(addr_o, ai_));             \
    c = fmaf(gf_, c, gi_ * gg_);                                             \
    float e2_ = __builtin_amdgcn_exp2f(-2.0f * LOG2E * c);                   \
    float r2_ = __builtin_amdgcn_rcpf(1.0f + e2_);                           \
    float th_ = fmaf(2.0f, r2_, -1.0f);                                      \
    hcur = go_ * th_;                                                        \
}

#define STEP8(base) STEP(base+0) STEP(base+1) STEP(base+2) STEP(base+3) \
                    STEP(base+4) STEP(base+5) STEP(base+6) STEP(base+7)

__global__ __launch_bounds__(256) void lstm_fused(
    const float* __restrict__ x,
    const float* __restrict__ Wih,
    const float* __restrict__ Whh,
    const float* __restrict__ bih,
    const float* __restrict__ bhh,
    const float* __restrict__ Wfc,
    const float* __restrict__ bfc,
    float* __restrict__ out)
{
    const int T   = 2048;
    const int tid = blockIdx.x * blockDim.x + threadIdx.x;
    const int b   = tid >> 6;            // one wave per batch element
    const int l   = threadIdx.x & 63;    // gate row
    const int j   = l & 15;              // hidden unit
    const int gate = l >> 4;             // 0:i 1:f 2:g 3:o

    // Probe DPP row_ror direction: after ror:1, lane l holds j from lane (l+-1)&15.
    int probe = __builtin_amdgcn_mov_dpp(j, 0x121, 0xF, 0xF, true);
    const int dir = (probe == ((j + 1) & 15)) ? 1 : -1;

    // Pre-rotated W_hh row: w[s] pairs with RORF(h, s) == h[(j + s*dir) & 15].
    float w[16];
#pragma unroll
    for (int s = 0; s < 16; ++s) {
        int k = (j + s * dir + 32) & 15;
        w[s] = Whh[l * 16 + k];
    }

    const float wih  = Wih[l];           // IN = 1
    const float bias = bih[l] + bhh[l];

    // sigmoid(x) = rcp(1 + exp2(-log2e * x)); tanh(x) = 2*rcp(1+exp2(-2log2e*x)) - 1
    const float mco = (gate == 2) ? (-2.0f * LOG2E) : (-LOG2E);
    const float aco = (gate == 2) ? 2.0f : 1.0f;
    const float bco = (gate == 2) ? -1.0f : 0.0f;

    // bpermute byte addresses for gathering i,f,g,o of unit j (all lanes replicate)
    const int addr_i = (j     ) << 2;
    const int addr_f = (j + 16) << 2;
    const int addr_g = (j + 32) << 2;
    const int addr_o = (j + 48) << 2;

    const float* xp = x + (size_t)b * T;
    float xblk = xp[l];                  // x staged 64 timesteps per VGPR

    float hcur = 0.0f, c = 0.0f;

#pragma unroll 1
    for (int blk = 0; blk < 32; ++blk) {
        const int nxt = (blk < 31) ? (blk + 1) : 31;
        float xnext = xp[nxt * 64 + l];  // prefetch next x block (vmcnt path)
        STEP8(0) STEP8(8) STEP8(16) STEP8(24)
        STEP8(32) STEP8(40) STEP8(48) STEP8(56)
        xblk = xnext;
    }

    // out[b] = sum_j Wfc[j]*h[j] + bfc ; h replicated 4x -> scale by 0.25
    float p = hcur * (Wfc[j] * 0.25f);
    p += __shfl_xor(p, 32);
    p += __shfl_xor(p, 16);
    p += __shfl_xor(p, 8);
    p += __shfl_xor(p, 4);
    p += __shfl_xor(p, 2);
    p += __shfl_xor(p, 1);
    if (l == 0) out[b] = p + bfc[0];
}

extern "C" void kernel_launch(void* const* d_in, const int* in_sizes, int n_in,
                              void* d_out, int out_size, void* d_ws, size_t ws_size,
                              hipStream_t stream) {
    const float* x   = (const float*)d_in[0];
    const float* Wih = (const float*)d_in[1];
    const float* Whh = (const float*)d_in[2];
    const float* bih = (const float*)d_in[3];
    const float* bhh = (const float*)d_in[4];
    const float* Wfc = (const float*)d_in[5];
    const float* bfc = (const float*)d_in[6];
    float* out = (float*)d_out;

    const int B = 2048;
    const int threads = 256;              // 4 waves/block, 1 batch elem per wave
    const int blocks = (B * 64) / threads; // 512 blocks -> 2 blocks/CU, 2 waves/SIMD
    hipLaunchKernelGGL(lstm_fused, dim3(blocks), dim3(threads), 0, stream,
                       x, Wih, Whh, bih, bhh, Wfc, bfc, out);
}

// Round 2
// 402.476 us; speedup vs baseline: 1.0685x; 1.0685x over previous
//
#include <hip/hip_runtime.h>

// LSTM: B=2048 independent sequences, T=2048 serial steps, H=16, IN=1.
// One wave per batch element: lane l = gate row l (i:0-15, f:16-31, g:32-47, o:48-63).
// h replicated per 16-lane DPP row; matvec via FUSED v_fmac_f32_dpp row_ror:n
// against pre-rotated, pre-scaled W_hh registers. Full fp32 recurrence.
// Constant folds: w/wih/bias pre-scaled by mco so exp2 takes the accumulator
// directly; c stored scaled by -2*log2e so tanh's exp2 takes c directly.

__device__ __forceinline__ float i2f(int i) { return __int_as_float(i); }
__device__ __forceinline__ int   f2i(float f) { return __float_as_int(f); }

#define LOG2E 1.44269504088896340736f

// Fused rotate+FMA: acc += h[(j +- n) & 15] * w   (one VALU instruction)
#define FMAC_DPP(acc, h_, w_, n)                                               \
    asm("v_fmac_f32_dpp %0, %1, %2 row_ror:" #n " row_mask:0xf bank_mask:0xf"  \
        : "+v"(acc) : "v"(h_), "v"(w_));

#define STEP(s_imm) {                                                        \
    float xs_ = i2f(__builtin_amdgcn_readlane(f2i(xblk), (s_imm)));          \
    float aA_ = fmaf(wih_s, xs_, bias_s);                                    \
    aA_ = fmaf(hcur, w[0], aA_);                                             \
    FMAC_DPP(aA_, hcur, w[1], 1)                                             \
    FMAC_DPP(aA_, hcur, w[2], 2)                                             \
    FMAC_DPP(aA_, hcur, w[3], 3)                                             \
    FMAC_DPP(aA_, hcur, w[4], 4)                                             \
    FMAC_DPP(aA_, hcur, w[5], 5)                                             \
    FMAC_DPP(aA_, hcur, w[6], 6)                                             \
    FMAC_DPP(aA_, hcur, w[7], 7)                                             \
    float aB_;                                                               \
    asm("v_mul_f32_dpp %0, %1, %2 row_ror:8 row_mask:0xf bank_mask:0xf"      \
        : "=v"(aB_) : "v"(hcur), "v"(w[8]));                                 \
    FMAC_DPP(aB_, hcur, w[9],  9)                                            \
    FMAC_DPP(aB_, hcur, w[10], 10)                                           \
    FMAC_DPP(aB_, hcur, w[11], 11)                                           \
    FMAC_DPP(aB_, hcur, w[12], 12)                                           \
    FMAC_DPP(aB_, hcur, w[13], 13)                                           \
    FMAC_DPP(aB_, hcur, w[14], 14)                                           \
    FMAC_DPP(aB_, hcur, w[15], 15)                                           \
    float acc_ = aA_ + aB_;                                                  \
    float e_   = __builtin_amdgcn_exp2f(acc_);          /* pre-scaled */     \
    float r_   = __builtin_amdgcn_rcpf(1.0f + e_);                           \
    float act_ = fmaf(aco, r_, bco);                                         \
    int   ai_  = f2i(act_);                                                  \
    float gi_  = i2f(__builtin_amdgcn_ds_bpermute(addr_i, ai_));             \
    float gf_  = i2f(__builtin_amdgcn_ds_bpermute(addr_f, ai_));             \
    float gg_  = i2f(__builtin_amdgcn_ds_bpermute(addr_g, ai_));             \
    float go_  = i2f(__builtin_amdgcn_ds_bpermute(addr_o, ai_));             \
    c = fmaf(gf_, c, gi_ * gg_);          /* c is scaled by -2*log2e */      \
    float e2_ = __builtin_amdgcn_exp2f(c);                                   \
    float r2_ = __builtin_amdgcn_rcpf(1.0f + e2_);                           \
    float th_ = fmaf(2.0f, r2_, -1.0f);                                      \
    hcur = go_ * th_;                                                        \
}

#define STEP8(base) STEP(base+0) STEP(base+1) STEP(base+2) STEP(base+3) \
                    STEP(base+4) STEP(base+5) STEP(base+6) STEP(base+7)

__global__ __launch_bounds__(256) void lstm_fused(
    const float* __restrict__ x,
    const float* __restrict__ Wih,
    const float* __restrict__ Whh,
    const float* __restrict__ bih,
    const float* __restrict__ bhh,
    const float* __restrict__ Wfc,
    const float* __restrict__ bfc,
    float* __restrict__ out)
{
    const int T   = 2048;
    const int tid = blockIdx.x * blockDim.x + threadIdx.x;
    const int b   = tid >> 6;            // one wave per batch element
    const int l   = threadIdx.x & 63;    // gate row
    const int j   = l & 15;              // hidden unit
    const int gate = l >> 4;             // 0:i 1:f 2:g 3:o

    // Probe DPP row_ror direction: after ror:1, lane l holds j from lane (l+-1)&15.
    int probe = __builtin_amdgcn_mov_dpp(j, 0x121, 0xF, 0xF, true);
    const int dir = (probe == ((j + 1) & 15)) ? 1 : -1;

    // sigmoid(z) = rcp(1 + exp2(-log2e*z)); tanh(z) = 2*rcp(1+exp2(-2log2e*z)) - 1
    const float mco = (gate == 2) ? (-2.0f * LOG2E) : (-LOG2E);
    // g-gate activation additionally folds the -2*log2e scale of the c state:
    // act_g' = -2log2e * (2r - 1) = (-4log2e)*r + 2log2e
    const float aco = (gate == 2) ? (-4.0f * LOG2E) : 1.0f;
    const float bco = (gate == 2) ? ( 2.0f * LOG2E) : 0.0f;

    // Pre-rotated + pre-scaled W_hh row: w[s] pairs with row_ror:s of h.
    float w[16];
#pragma unroll
    for (int s = 0; s < 16; ++s) {
        int k = (j + s * dir + 32) & 15;
        w[s] = Whh[l * 16 + k] * mco;
    }

    const float wih_s  = Wih[l] * mco;            // IN = 1
    const float bias_s = (bih[l] + bhh[l]) * mco;

    // bpermute byte addresses for gathering i,f,g,o of unit j (all lanes replicate)
    const int addr_i = (j     ) << 2;
    const int addr_f = (j + 16) << 2;
    const int addr_g = (j + 32) << 2;
    const int addr_o = (j + 48) << 2;

    const float* xp = x + (size_t)b * T;
    float xblk = xp[l];                  // x staged 64 timesteps per VGPR

    float hcur = 0.0f, c = 0.0f;         // c holds -2log2e * c_real

#pragma unroll 1
    for (int blk = 0; blk < 32; ++blk) {
        const int nxt = (blk < 31) ? (blk + 1) : 31;
        float xnext = xp[nxt * 64 + l];  // prefetch next x block (vmcnt path)
        STEP8(0) STEP8(8) STEP8(16) STEP8(24)
        STEP8(32) STEP8(40) STEP8(48) STEP8(56)
        xblk = xnext;
    }

    // out[b] = sum_j Wfc[j]*h[j] + bfc ; h replicated 4x -> scale by 0.25
    float p = hcur * (Wfc[j] * 0.25f);
    p += __shfl_xor(p, 32);
    p += __shfl_xor(p, 16);
    p += __shfl_xor(p, 8);
    p += __shfl_xor(p, 4);
    p += __shfl_xor(p, 2);
    p += __shfl_xor(p, 1);
    if (l == 0) out[b] = p + bfc[0];
}

extern "C" void kernel_launch(void* const* d_in, const int* in_sizes, int n_in,
                              void* d_out, int out_size, void* d_ws, size_t ws_size,
                              hipStream_t stream) {
    const float* x   = (const float*)d_in[0];
    const float* Wih = (const float*)d_in[1];
    const float* Whh = (const float*)d_in[2];
    const float* bih = (const float*)d_in[3];
    const float* bhh = (const float*)d_in[4];
    const float* Wfc = (const float*)d_in[5];
    const float* bfc = (const float*)d_in[6];
    float* out = (float*)d_out;

    const int B = 2048;
    const int threads = 256;               // 4 waves/block, 1 batch elem per wave
    const int blocks = (B * 64) / threads; // 512 blocks -> 2 waves/SIMD
    hipLaunchKernelGGL(lstm_fused, dim3(blocks), dim3(threads), 0, stream,
                       x, Wih, Whh, bih, bhh, Wfc, bfc, out);
}